// Round 10
// baseline (113.350 us; speedup 1.0000x reference)
//
#include <hip/hip_runtime.h>

// AxonalConnections: out[n,b,:,:] = sum over 4 incoming edges (src -> n) of
//   spikes[src,b] * masks[src] * weights[e]
// Topology is compile-time: src(e) = e>>2, dst(e) = (src + (e&3) + 1) & 7.
//
// Lessons:
//  r1: compiler sinks re-loadable loads -> 4x weight re-reads.
//  r3: f32x2 single-pass zero-redundancy: 92 us.
//  r4: any 2nd input pass misses L3 (streams > 256MB) -> +120MB HBM, regress.
//  r5: TLP with redundant lanes hurts.  r6: f32x4 doesn't help.
//  r7: FULL 72-load burst + sched_barrier(0): 85.9 us (best). But the burst
//      lives in AGPRs (VGPR=80, alloc ~224) -> only 2 waves/SIMD (occ 25%).
//  r8: stores interleaved into compute share vmcnt with loads -> regress.
//  r9: nontemporal LOADS evict inputs from L2/L3 read path -> regress (93us).
//
// r10: test the untested axis = moderate MLP x 4 waves/SIMD. Two-deep
// software pipeline over sources: issue src+1's 9 loads (m,s[4],w[4]),
// fence, compute src (prescale + 32 FMA), fence. Peak live ~115 regs ->
// launch_bounds(256,4) doubles resident waves vs r7 while each wave still
// keeps 9-18 loads in flight. Stores stay in the tail; NT stores only.
// Ideal HBM traffic: 288 MiB read + 128 MiB write (~69 us @ 6.3 TB/s).

#define HW (1024 * 1024)   // H*W pixels
#define NN 8               // nodes
#define NB 4               // batch

typedef float f32x2 __attribute__((ext_vector_type(2)));

__global__ __launch_bounds__(256, 4) void axon_kernel(
    const float* __restrict__ spikes,   // [N, B, HW]
    const float* __restrict__ masks,    // [N, HW]
    const float* __restrict__ weights,  // [E, HW]
    float* __restrict__ out)            // [N, B, HW]
{
    const int t = blockIdx.x * blockDim.x + threadIdx.x;  // 0 .. HW/2 - 1
    const int p = t * 2;                                  // float offset in a plane

    f32x2 acc[NN][NB];
#pragma unroll
    for (int n = 0; n < NN; ++n)
#pragma unroll
        for (int b = 0; b < NB; ++b) acc[n][b] = (f32x2)(0.0f);

    // double-buffered stage registers: one source's inputs = 9 loads (18 regs)
    f32x2 m2[2], s2[2][NB], w2[2][4];

    // prologue: issue stage 0
    m2[0] = *reinterpret_cast<const f32x2*>(masks + 0 * HW + p);
#pragma unroll
    for (int b = 0; b < NB; ++b)
        s2[0][b] = *reinterpret_cast<const f32x2*>(spikes + (0 * NB + b) * HW + p);
#pragma unroll
    for (int k = 0; k < 4; ++k)
        w2[0][k] = *reinterpret_cast<const f32x2*>(weights + (0 * 4 + k) * HW + p);

#pragma unroll
    for (int src = 0; src < NN; ++src) {
        const int cur = src & 1;
        const int nxt = cur ^ 1;

        // issue next stage's loads while this stage's data arrives
        if (src + 1 < NN) {
            const int sn = src + 1;
            m2[nxt] = *reinterpret_cast<const f32x2*>(masks + sn * HW + p);
#pragma unroll
            for (int b = 0; b < NB; ++b)
                s2[nxt][b] = *reinterpret_cast<const f32x2*>(spikes + (sn * NB + b) * HW + p);
#pragma unroll
            for (int k = 0; k < 4; ++k)
                w2[nxt][k] = *reinterpret_cast<const f32x2*>(weights + (sn * 4 + k) * HW + p);
        }
        __builtin_amdgcn_sched_barrier(0);   // loads above, compute below

        // compute stage src
        f32x2 sm[NB];
#pragma unroll
        for (int b = 0; b < NB; ++b) sm[b] = s2[cur][b] * m2[cur];

#pragma unroll
        for (int k = 0; k < 4; ++k) {
            const int dst = (src + k + 1) & 7;
#pragma unroll
            for (int b = 0; b < NB; ++b) {
                acc[dst][b].x = fmaf(sm[b].x, w2[cur][k].x, acc[dst][b].x);
                acc[dst][b].y = fmaf(sm[b].y, w2[cur][k].y, acc[dst][b].y);
            }
        }
        __builtin_amdgcn_sched_barrier(0);   // keep stage boundaries intact
    }

    // stores stay in the tail (r8 lesson)
#pragma unroll
    for (int n = 0; n < NN; ++n)
#pragma unroll
        for (int b = 0; b < NB; ++b)
            __builtin_nontemporal_store(
                acc[n][b], reinterpret_cast<f32x2*>(out + (n * NB + b) * HW + p));
}

extern "C" void kernel_launch(void* const* d_in, const int* in_sizes, int n_in,
                              void* d_out, int out_size, void* d_ws, size_t ws_size,
                              hipStream_t stream) {
    const float* spikes  = (const float*)d_in[0];  // [8,4,1024,1024]
    const float* masks   = (const float*)d_in[1];  // [8,1024,1024]
    const float* weights = (const float*)d_in[2];  // [32,1024,1024]
    float* out = (float*)d_out;                    // [8,4,1024,1024]

    const int threads = 256;
    const int blocks  = (HW / 2) / threads;        // 2048 blocks, 1 thread / 2 pixels
    axon_kernel<<<blocks, threads, 0, stream>>>(spikes, masks, weights, out);
}

// Round 11
// 88.785 us; speedup vs baseline: 1.2767x; 1.2767x over previous
//
#include <hip/hip_runtime.h>

// AxonalConnections: out[n,b,:,:] = sum over 4 incoming edges (src -> n) of
//   spikes[src,b] * masks[src] * weights[e]
// Topology is compile-time: src(e) = e>>2, dst(e) = (src + (e&3) + 1) & 7.
//
// FINAL (= round-7 kernel, best of 10 rounds at 85.9 us):
//  r1: compiler sinks re-loadable loads -> 4x weight re-reads.
//  r3: f32x2 single-pass zero-redundancy: 92 us.
//  r4: any 2nd input pass misses L3 (streams > 256MB) -> +120MB HBM, regress.
//  r5: TLP (occ 78%) doesn't help; redundant lanes hurt (104 us).
//  r6: f32x4 doesn't help (110 us; inst count not the limiter).
//  r7: FULL 72-load burst + sched_barrier(0): 85.9 us  <= THIS KERNEL.
//  r8: stores interleaved into compute share vmcnt with loads -> 94.8 us.
//  r9: nontemporal LOADS evict inputs from L2/L3 read path -> 93.2 us.
//  r10: forced 4-wave pipeline spills to scratch (+108MB traffic) -> 113 us.
//
// Steady state: 436 MB logical / 85.9 us = 5.1 TB/s (81% of the 6.3 TB/s
// float4-copy ceiling); HBM carries 278 MB (L3 serves ~140 MB of inputs);
// MLP per SIMD ~73 KB outstanding >> 2.3 KB needed -> latency fully hidden.
// All structural axes probed; everything off this point regresses.

#define HW (1024 * 1024)   // H*W pixels
#define NN 8               // nodes
#define NB 4               // batch

typedef float f32x2 __attribute__((ext_vector_type(2)));

__global__ __launch_bounds__(256, 2) void axon_kernel(
    const float* __restrict__ spikes,   // [N, B, HW]
    const float* __restrict__ masks,    // [N, HW]
    const float* __restrict__ weights,  // [E, HW]
    float* __restrict__ out)            // [N, B, HW]
{
    const int t = blockIdx.x * blockDim.x + threadIdx.x;  // 0 .. HW/2 - 1
    const int p = t * 2;                                  // float offset in a plane

    // ---- one big load burst: every input byte this thread will ever touch ----
    f32x2 m[NN], s[NN][NB], w[32];
#pragma unroll
    for (int n = 0; n < NN; ++n)
        m[n] = *reinterpret_cast<const f32x2*>(masks + n * HW + p);
#pragma unroll
    for (int n = 0; n < NN; ++n)
#pragma unroll
        for (int b = 0; b < NB; ++b)
            s[n][b] = *reinterpret_cast<const f32x2*>(spikes + (n * NB + b) * HW + p);
#pragma unroll
    for (int e = 0; e < 32; ++e)
        w[e] = *reinterpret_cast<const f32x2*>(weights + e * HW + p);

    // fence: scheduler may not sink any of the loads above into the compute
    __builtin_amdgcn_sched_barrier(0);

    f32x2 acc[NN][NB];
#pragma unroll
    for (int n = 0; n < NN; ++n)
#pragma unroll
        for (int b = 0; b < NB; ++b) acc[n][b] = (f32x2)(0.0f);

#pragma unroll
    for (int src = 0; src < NN; ++src) {
        // pre-scale spikes by source mask (feeds all 4 outgoing edges)
#pragma unroll
        for (int b = 0; b < NB; ++b) s[src][b] *= m[src];

#pragma unroll
        for (int k = 0; k < 4; ++k) {
            const int e   = src * 4 + k;
            const int dst = (src + k + 1) & 7;
#pragma unroll
            for (int b = 0; b < NB; ++b) {
                acc[dst][b].x = fmaf(s[src][b].x, w[e].x, acc[dst][b].x);
                acc[dst][b].y = fmaf(s[src][b].y, w[e].y, acc[dst][b].y);
            }
        }
    }

    // stores stay in the tail (r8 lesson: they share vmcnt with loads)
#pragma unroll
    for (int n = 0; n < NN; ++n)
#pragma unroll
        for (int b = 0; b < NB; ++b)
            __builtin_nontemporal_store(
                acc[n][b], reinterpret_cast<f32x2*>(out + (n * NB + b) * HW + p));
}

extern "C" void kernel_launch(void* const* d_in, const int* in_sizes, int n_in,
                              void* d_out, int out_size, void* d_ws, size_t ws_size,
                              hipStream_t stream) {
    const float* spikes  = (const float*)d_in[0];  // [8,4,1024,1024]
    const float* masks   = (const float*)d_in[1];  // [8,1024,1024]
    const float* weights = (const float*)d_in[2];  // [32,1024,1024]
    float* out = (float*)d_out;                    // [8,4,1024,1024]

    const int threads = 256;
    const int blocks  = (HW / 2) / threads;        // 2048 blocks, 1 thread / 2 pixels
    axon_kernel<<<blocks, threads, 0, stream>>>(spikes, masks, weights, out);
}